// Round 3
// baseline (1460.258 us; speedup 1.0000x reference)
//
#include <hip/hip_runtime.h>
#include <math.h>

typedef short  s16x8 __attribute__((ext_vector_type(8)));
typedef short  s16x4 __attribute__((ext_vector_type(4)));
typedef float  f32x4 __attribute__((ext_vector_type(4)));

#define DEV static __device__ __forceinline__

DEV float b2f(unsigned short h) {
    unsigned int u = ((unsigned int)h) << 16;
    float f; __builtin_memcpy(&f, &u, 4); return f;
}
DEV unsigned short f2b(float f) {
    unsigned int u; __builtin_memcpy(&u, &f, 4);
    unsigned int r = (u + 0x7fffu + ((u >> 16) & 1u)) >> 16;
    return (unsigned short)r;
}

template<bool F32>
DEV float ld1(const void* p, size_t i) {
    if constexpr (F32) return ((const float*)p)[i];
    else return b2f(((const unsigned short*)p)[i]);
}

// Load 8 consecutive elements as bf16 bits (converting from fp32 if needed).
template<bool F32>
DEV s16x8 ld8(const void* p, size_t eidx) {
    if constexpr (F32) {
        const float* f = (const float*)p + eidx;
        f32x4 a = *(const f32x4*)f;
        f32x4 b = *(const f32x4*)(f + 4);
        s16x8 o;
        o[0]=(short)f2b(a[0]); o[1]=(short)f2b(a[1]); o[2]=(short)f2b(a[2]); o[3]=(short)f2b(a[3]);
        o[4]=(short)f2b(b[0]); o[5]=(short)f2b(b[1]); o[6]=(short)f2b(b[2]); o[7]=(short)f2b(b[3]);
        return o;
    } else {
        return *(const s16x8*)((const unsigned short*)p + eidx);
    }
}

// ---------------------------------------------------------------------------
// Dtype probe: bf16 word -> bits[14:7] are the low element's exponent,
// concentrated in [0x70,0x87] for N(0,1). fp32 word -> those bits are random
// mantissa (~9% hit rate). flag: 0 = bf16, 1 = fp32.
// ---------------------------------------------------------------------------
__global__ __launch_bounds__(256) void dtype_probe(
    const unsigned int* __restrict__ q, int* __restrict__ flag)
{
    int t = threadIdx.x;
    int hits = 0;
    for (int i = t; i < 2048; i += 256) {
        unsigned e0 = (q[i] >> 7) & 0xFFu;
        hits += (e0 >= 0x70u && e0 <= 0x87u) ? 1 : 0;
    }
#pragma unroll
    for (int m = 32; m >= 1; m >>= 1) hits += __shfl_xor(hits, m);
    __shared__ int sh[4];
    if ((t & 63) == 0) sh[t >> 6] = hits;
    __syncthreads();
    if (t == 0) *flag = (sh[0] + sh[1] + sh[2] + sh[3] > 1024) ? 0 : 1;
}

// ---------------------------------------------------------------------------
// Mask prep: handles int32 (per-spec) or byte-packed bool staging.
// ---------------------------------------------------------------------------
__global__ __launch_bounds__(1024) void mask_prep(
    const unsigned int* __restrict__ w, const unsigned char* __restrict__ bytes,
    int* __restrict__ clean)
{
    __shared__ int flag;
    const int t = threadIdx.x;
    if (t == 0) flag = 0;
    __syncthreads();
    unsigned int a = w[t], b = w[t + 1024];
    if (a > 1u || b > 1u) flag = 1;
    __syncthreads();
    const int f = flag;
#pragma unroll
    for (int i = 0; i < 8; i++) {
        int c = t * 8 + i;
        clean[c] = f ? (int)(bytes[c] != 0) : (int)(w[c] != 0);
    }
}

// ---------------------------------------------------------------------------
// LayerNorm(1024). Input dtype XF32, weight/bias dtype WF32. Output bf16.
// ---------------------------------------------------------------------------
template<bool XF32, bool WF32>
__global__ __launch_bounds__(256) void ln_k(
    const int* __restrict__ flagp, int want,
    const void* __restrict__ x, const void* __restrict__ wgt,
    const void* __restrict__ bias, unsigned short* __restrict__ y)
{
    if (*flagp != want) return;
    const int row = blockIdx.x, t = threadIdx.x;
    const int w = t >> 6, lane = t & 63;
    float f0, f1, f2, f3;
    if constexpr (XF32) {
        f32x4 v = *(const f32x4*)((const float*)x + (size_t)row * 1024 + t * 4);
        f0 = v[0]; f1 = v[1]; f2 = v[2]; f3 = v[3];
    } else {
        s16x4 v = *(const s16x4*)((const unsigned short*)x + (size_t)row * 1024 + t * 4);
        f0 = b2f((unsigned short)v[0]); f1 = b2f((unsigned short)v[1]);
        f2 = b2f((unsigned short)v[2]); f3 = b2f((unsigned short)v[3]);
    }
    __shared__ float red[4];
    float s = f0 + f1 + f2 + f3;
#pragma unroll
    for (int m = 32; m >= 1; m >>= 1) s += __shfl_xor(s, m);
    if (lane == 0) red[w] = s;
    __syncthreads();
    float mu = (red[0] + red[1] + red[2] + red[3]) * (1.0f / 1024.0f);
    float d0 = f0 - mu, d1 = f1 - mu, d2 = f2 - mu, d3 = f3 - mu;
    float q = d0 * d0 + d1 * d1 + d2 * d2 + d3 * d3;
#pragma unroll
    for (int m = 32; m >= 1; m >>= 1) q += __shfl_xor(q, m);
    __syncthreads();
    if (lane == 0) red[w] = q;
    __syncthreads();
    float var = (red[0] + red[1] + red[2] + red[3]) * (1.0f / 1024.0f);
    float rs = rsqrtf(var + 1e-5f);
    s16x4 vo;
    vo[0] = (short)f2b(d0 * rs * ld1<WF32>(wgt, t*4+0) + ld1<WF32>(bias, t*4+0));
    vo[1] = (short)f2b(d1 * rs * ld1<WF32>(wgt, t*4+1) + ld1<WF32>(bias, t*4+1));
    vo[2] = (short)f2b(d2 * rs * ld1<WF32>(wgt, t*4+2) + ld1<WF32>(bias, t*4+2));
    vo[3] = (short)f2b(d3 * rs * ld1<WF32>(wgt, t*4+3) + ld1<WF32>(bias, t*4+3));
    *(s16x4*)&y[(size_t)row * 1024 + t * 4] = vo;
}

// ---------------------------------------------------------------------------
// GEMM: C[M,N] = A[M,K](bf16) @ W[N,:]^T (+bias)(+gelu)(+res).
// W leading dim = ldw (elements). fp32 accumulate. 128x128 tile, BK=32.
// ---------------------------------------------------------------------------
template<bool WF32, bool RESF32, bool OUTF32>
__global__ __launch_bounds__(256) void gemm_bt(
    const int* __restrict__ flagp, int want,
    const unsigned short* __restrict__ A, const void* __restrict__ W,
    const void* __restrict__ bias, const void* __restrict__ res,
    void* __restrict__ C, int M, int N, int Kd, int ldw, int act)
{
    if (*flagp != want) return;
    __shared__ unsigned short As[128 * 32];
    __shared__ unsigned short Bs[128 * 32];
    const int t = threadIdx.x;
    const int m0 = blockIdx.y * 128, n0 = blockIdx.x * 128;
    const int w = t >> 6, lane = t & 63, quad = lane >> 4, l16 = lane & 15;
    const int wm = (w >> 1) * 64, wn = (w & 1) * 64;
    const f32x4 zero = {0.f, 0.f, 0.f, 0.f};
    f32x4 acc[4][4];
#pragma unroll
    for (int i = 0; i < 4; i++)
#pragma unroll
        for (int j = 0; j < 4; j++) acc[i][j] = zero;
    const int r0 = t >> 2, c0 = (t & 3) * 8;
    for (int kt = 0; kt < Kd; kt += 32) {
        *(s16x8*)&As[r0 * 32 + c0]        = *(const s16x8*)&A[(size_t)(m0 + r0) * Kd + kt + c0];
        *(s16x8*)&As[(r0 + 64) * 32 + c0] = *(const s16x8*)&A[(size_t)(m0 + r0 + 64) * Kd + kt + c0];
        *(s16x8*)&Bs[r0 * 32 + c0]        = ld8<WF32>(W, (size_t)(n0 + r0) * ldw + kt + c0);
        *(s16x8*)&Bs[(r0 + 64) * 32 + c0] = ld8<WF32>(W, (size_t)(n0 + r0 + 64) * ldw + kt + c0);
        __syncthreads();
        s16x8 af[4], bfr[4];
#pragma unroll
        for (int i = 0; i < 4; i++) {
            af[i]  = *(const s16x8*)&As[(wm + i * 16 + l16) * 32 + quad * 8];
            bfr[i] = *(const s16x8*)&Bs[(wn + i * 16 + l16) * 32 + quad * 8];
        }
#pragma unroll
        for (int mi = 0; mi < 4; mi++)
#pragma unroll
            for (int ni = 0; ni < 4; ni++)
                acc[mi][ni] = __builtin_amdgcn_mfma_f32_16x16x32_bf16(af[mi], bfr[ni], acc[mi][ni], 0, 0, 0);
        __syncthreads();
    }
#pragma unroll
    for (int mi = 0; mi < 4; mi++)
#pragma unroll
        for (int ni = 0; ni < 4; ni++)
#pragma unroll
            for (int r = 0; r < 4; r++) {
                int gr = m0 + wm + mi * 16 + quad * 4 + r;
                int gc = n0 + wn + ni * 16 + l16;
                float v = acc[mi][ni][r];
                if (bias) v += ld1<WF32>(bias, gc);
                if (act) v = 0.5f * v * (1.f + erff(v * 0.70710678118f));
                if (res) v += ld1<RESF32>(res, (size_t)gr * N + gc);
                size_t ci = (size_t)gr * N + gc;
                if constexpr (OUTF32) ((float*)C)[ci] = v;
                else ((unsigned short*)C)[ci] = f2b(v);
            }
}

// ---------------------------------------------------------------------------
// V transpose: vt[((b*16+h)*64+d)*1024 + k] = vp[(b*1024+k)*1024 + h*64 + d]
// ---------------------------------------------------------------------------
__global__ __launch_bounds__(256) void transpose_v(
    const unsigned short* __restrict__ vp, unsigned short* __restrict__ vt)
{
    int t = blockIdx.x * 256 + threadIdx.x;   // 2^20 threads
    int k8 = (t & 127) * 8;
    int d  = (t >> 7) & 63;
    int h  = (t >> 13) & 15;
    int b  = t >> 17;
    s16x8 v;
#pragma unroll
    for (int j = 0; j < 8; j++)
        v[j] = (short)vp[(size_t)((b << 10) + k8 + j) * 1024 + (h << 6) + d];
    *(s16x8*)&vt[(size_t)t * 8] = v;
}

// ---------------------------------------------------------------------------
// Flash attention (all-internal bf16; dtype-independent).
// Block = (b, 16 q-rows); wave w handles heads 4w..4w+3.
// ---------------------------------------------------------------------------
__global__ __launch_bounds__(256) void flash_attn(
    const unsigned short* __restrict__ qp, const unsigned short* __restrict__ kp,
    const unsigned short* __restrict__ vt, const int* __restrict__ mask,
    unsigned short* __restrict__ ao, float* __restrict__ ml)
{
    const int b = blockIdx.x, q0 = blockIdx.y * 16;
    const int t = threadIdx.x, w = t >> 6, lane = t & 63, quad = lane >> 4, l16 = lane & 15;
    const int h0 = w * 4;
    __shared__ unsigned short Pst[4][16 * 40];
    unsigned short* P = Pst[w];
    const float NEGINF = -__builtin_inff();
    const f32x4 zero = {0.f, 0.f, 0.f, 0.f};

    s16x8 qf[4][2];
#pragma unroll
    for (int hh = 0; hh < 4; hh++)
#pragma unroll
        for (int s2 = 0; s2 < 2; s2++)
            qf[hh][s2] = *(const s16x8*)&qp[(size_t)(b * 1024 + q0 + l16) * 1024 + (h0 + hh) * 64 + s2 * 32 + quad * 8];

    f32x4 O[4][4];
    float m_r[4][4], l_r[4][4];
#pragma unroll
    for (int hh = 0; hh < 4; hh++) {
#pragma unroll
        for (int dt = 0; dt < 4; dt++) O[hh][dt] = zero;
#pragma unroll
        for (int r = 0; r < 4; r++) { m_r[hh][r] = NEGINF; l_r[hh][r] = 0.f; }
    }

    for (int kt = 0; kt < 1024; kt += 32) {
        const int c0i = kt + l16, c1i = c0i + 16;
        const bool v0 = mask[b * 1024 + c0i] != 0;
        const bool v1 = mask[b * 1024 + c1i] != 0;
#pragma unroll
        for (int hh = 0; hh < 4; hh++) {
            const size_t kb0 = (size_t)(b * 1024 + c0i) * 1024 + (h0 + hh) * 64 + quad * 8;
            const size_t kb1 = (size_t)(b * 1024 + c1i) * 1024 + (h0 + hh) * 64 + quad * 8;
            s16x8 b00 = *(const s16x8*)&kp[kb0];
            s16x8 b01 = *(const s16x8*)&kp[kb0 + 32];
            s16x8 b10 = *(const s16x8*)&kp[kb1];
            s16x8 b11 = *(const s16x8*)&kp[kb1 + 32];
            f32x4 S0 = __builtin_amdgcn_mfma_f32_16x16x32_bf16(qf[hh][0], b00, zero, 0, 0, 0);
            S0 = __builtin_amdgcn_mfma_f32_16x16x32_bf16(qf[hh][1], b01, S0, 0, 0, 0);
            f32x4 S1 = __builtin_amdgcn_mfma_f32_16x16x32_bf16(qf[hh][0], b10, zero, 0, 0, 0);
            S1 = __builtin_amdgcn_mfma_f32_16x16x32_bf16(qf[hh][1], b11, S1, 0, 0, 0);
            float e0[4], e1[4];
#pragma unroll
            for (int r = 0; r < 4; r++) {
                float s0 = v0 ? S0[r] * 0.125f : NEGINF;
                float s1 = v1 ? S1[r] * 0.125f : NEGINF;
                float mt = fmaxf(s0, s1);
#pragma unroll
                for (int off = 1; off < 16; off <<= 1) mt = fmaxf(mt, __shfl_xor(mt, off));
                float mo = m_r[hh][r];
                float mn = fmaxf(mo, mt);
                float al = (mo == NEGINF) ? 0.f : __expf(mo - mn);
                float x0 = v0 ? __expf(s0 - mn) : 0.f;
                float x1 = v1 ? __expf(s1 - mn) : 0.f;
                float rsum = x0 + x1;
#pragma unroll
                for (int off = 1; off < 16; off <<= 1) rsum += __shfl_xor(rsum, off);
                m_r[hh][r] = mn;
                l_r[hh][r] = l_r[hh][r] * al + rsum;
#pragma unroll
                for (int dt = 0; dt < 4; dt++) O[hh][dt][r] *= al;
                e0[r] = x0; e1[r] = x1;
            }
            // P round-trip through LDS. Uniform trip counts for all waves, so
            // real barriers are legal; they make the write->read->next-write
            // ordering airtight for both HW and compiler.
#pragma unroll
            for (int r = 0; r < 4; r++) {
                P[(quad * 4 + r) * 40 + l16]      = f2b(e0[r]);
                P[(quad * 4 + r) * 40 + 16 + l16] = f2b(e1[r]);
            }
            __syncthreads();
            s16x8 pf = *(const s16x8*)&P[l16 * 40 + quad * 8];
            __syncthreads();
#pragma unroll
            for (int dt = 0; dt < 4; dt++) {
                s16x8 vf = *(const s16x8*)&vt[(size_t)((b * 16 + h0 + hh) * 64 + dt * 16 + l16) * 1024 + kt + quad * 8];
                O[hh][dt] = __builtin_amdgcn_mfma_f32_16x16x32_bf16(pf, vf, O[hh][dt], 0, 0, 0);
            }
        }
    }
#pragma unroll
    for (int hh = 0; hh < 4; hh++) {
        float li[4];
#pragma unroll
        for (int r = 0; r < 4; r++)
            li[r] = (l_r[hh][r] > 0.f) ? 1.f / l_r[hh][r] : 0.f;
#pragma unroll
        for (int dt = 0; dt < 4; dt++)
#pragma unroll
            for (int r = 0; r < 4; r++) {
                int qrow = q0 + quad * 4 + r;
                ao[(size_t)(b * 1024 + qrow) * 1024 + (h0 + hh) * 64 + dt * 16 + l16] = f2b(O[hh][dt][r] * li[r]);
            }
        if (l16 == 0) {
#pragma unroll
            for (int r = 0; r < 4; r++) {
                int qrow = q0 + quad * 4 + r;
                size_t ix = ((size_t)(b * 16 + h0 + hh) * 1024 + qrow) * 2;
                ml[ix] = m_r[hh][r]; ml[ix + 1] = l_r[hh][r];
            }
        }
    }
}

// ---------------------------------------------------------------------------
// Mean-over-heads attention weights. Output dtype templated.
// ---------------------------------------------------------------------------
template<bool OUTF32>
__global__ __launch_bounds__(256) void attn_mean_k(
    const int* __restrict__ flagp, int want,
    const unsigned short* __restrict__ qp, const unsigned short* __restrict__ kp,
    const int* __restrict__ mask, const float* __restrict__ ml,
    void* __restrict__ ow)
{
    if (*flagp != want) return;
    const int b = blockIdx.x, q0 = blockIdx.y * 16;
    const int t = threadIdx.x, w = t >> 6, lane = t & 63, quad = lane >> 4, l16 = lane & 15;
    const int kbase = w * 256;
    const f32x4 zero = {0.f, 0.f, 0.f, 0.f};
    f32x4 acc[16];
#pragma unroll
    for (int i = 0; i < 16; i++) acc[i] = zero;
    unsigned vm = 0;
#pragma unroll
    for (int i = 0; i < 16; i++)
        if (mask[b * 1024 + kbase + i * 16 + l16]) vm |= 1u << i;
    for (int h = 0; h < 16; h++) {
        const size_t qb = (size_t)(b * 1024 + q0 + l16) * 1024 + h * 64 + quad * 8;
        s16x8 a0 = *(const s16x8*)&qp[qb];
        s16x8 a1 = *(const s16x8*)&qp[qb + 32];
        float mrow[4], lirow[4];
#pragma unroll
        for (int r = 0; r < 4; r++) {
            size_t ix = ((size_t)(b * 16 + h) * 1024 + q0 + quad * 4 + r) * 2;
            float lv = ml[ix + 1];
            mrow[r] = ml[ix]; lirow[r] = (lv > 0.f) ? 1.f / lv : 0.f;
        }
#pragma unroll
        for (int i = 0; i < 16; i++) {
            const size_t kb = (size_t)(b * 1024 + kbase + i * 16 + l16) * 1024 + h * 64 + quad * 8;
            s16x8 b0 = *(const s16x8*)&kp[kb];
            s16x8 b1 = *(const s16x8*)&kp[kb + 32];
            f32x4 S = __builtin_amdgcn_mfma_f32_16x16x32_bf16(a0, b0, zero, 0, 0, 0);
            S = __builtin_amdgcn_mfma_f32_16x16x32_bf16(a1, b1, S, 0, 0, 0);
            if ((vm >> i) & 1) {
#pragma unroll
                for (int r = 0; r < 4; r++)
                    acc[i][r] += __expf(S[r] * 0.125f - mrow[r]) * lirow[r];
            }
        }
    }
#pragma unroll
    for (int i = 0; i < 16; i++)
#pragma unroll
        for (int r = 0; r < 4; r++) {
            int qrow = q0 + quad * 4 + r;
            size_t oi = (size_t)(b * 1024 + qrow) * 1024 + kbase + i * 16 + l16;
            float v = acc[i][r] * 0.0625f;
            if constexpr (OUTF32) ((float*)ow)[oi] = v;
            else ((unsigned short*)ow)[oi] = f2b(v);
        }
}

// ---------------------------------------------------------------------------
extern "C" void kernel_launch(void* const* d_in, const int* in_sizes, int n_in,
                              void* d_out, int out_size, void* d_ws, size_t ws_size,
                              hipStream_t stream) {
    const void* query = d_in[0];
    const void* keyv  = d_in[1];
    const void* maskr = d_in[2];
    const void* lqw = d_in[3];  const void* lqb = d_in[4];
    const void* lkw = d_in[5];  const void* lkb = d_in[6];
    const void* lfw = d_in[7];  const void* lfb = d_in[8];
    const void* ipw = d_in[9];  const void* ipb = d_in[10];
    const void* opw = d_in[11]; const void* opb = d_in[12];
    const void* w1  = d_in[13]; const void* b1  = d_in[14];
    const void* w2  = d_in[15]; const void* b2  = d_in[16];

    char* ws = (char*)d_ws;
    const size_t MB = 1024 * 1024;
    // Layout (MiB): qn 0-16, kvn 16-32, qpj 32-48, kpj 48-64, vpj 64-80,
    // vtr 80-96, ml 96-97, cm 97+, flag 97.25. Reuse: aco 0-16, xbf(fp32)
    // 16-48, hn 48-64, g 64-96 (two 2048-wide FFN chunks). Peak ~97.3 MB.
    unsigned short* qn  = (unsigned short*)(ws + 0 * MB);
    unsigned short* kvn = (unsigned short*)(ws + 16 * MB);
    unsigned short* qpj = (unsigned short*)(ws + 32 * MB);
    unsigned short* kpj = (unsigned short*)(ws + 48 * MB);
    unsigned short* vpj = (unsigned short*)(ws + 64 * MB);
    unsigned short* vtr = (unsigned short*)(ws + 80 * MB);
    float*          ml  = (float*)(ws + 96 * MB);
    int*            cm  = (int*)(ws + 97 * MB);
    int*            fl  = (int*)(ws + 97 * MB + 256 * 1024);
    unsigned short* aco = (unsigned short*)(ws + 0 * MB);
    float*          xbf = (float*)(ws + 16 * MB);
    unsigned short* hn  = (unsigned short*)(ws + 48 * MB);
    unsigned short* g   = (unsigned short*)(ws + 64 * MB);

    const size_t QD = (size_t)8 * 1024 * 1024;   // 8,388,608 elements per output
    void* ow16 = (void*)((unsigned short*)d_out + QD);
    void* ow32 = (void*)((float*)d_out + QD);

    // element-offset helpers per dtype variant
    const unsigned short* ipw16 = (const unsigned short*)ipw;
    const float*          ipw32 = (const float*)ipw;
    const unsigned short* ipb16 = (const unsigned short*)ipb;
    const float*          ipb32 = (const float*)ipb;
    const unsigned short* w116  = (const unsigned short*)w1;
    const float*          w132  = (const float*)w1;
    const unsigned short* b116  = (const unsigned short*)b1;
    const float*          b132  = (const float*)b1;
    const unsigned short* w216  = (const unsigned short*)w2;
    const float*          w232  = (const float*)w2;

    dtype_probe<<<1, 256, 0, stream>>>((const unsigned int*)query, fl);
    mask_prep<<<1, 1024, 0, stream>>>((const unsigned int*)maskr, (const unsigned char*)maskr, cm);

    // LayerNorms (input + weights follow global dtype)
    ln_k<false,false><<<8192, 256, 0, stream>>>(fl, 0, query, lqw, lqb, qn);
    ln_k<true ,true ><<<8192, 256, 0, stream>>>(fl, 1, query, lqw, lqb, qn);
    ln_k<false,false><<<8192, 256, 0, stream>>>(fl, 0, keyv, lkw, lkb, kvn);
    ln_k<true ,true ><<<8192, 256, 0, stream>>>(fl, 1, keyv, lkw, lkb, kvn);

    // Projections (out bf16)
    gemm_bt<false,false,false><<<dim3(8,64), 256, 0, stream>>>(fl, 0, qn, ipw16, ipb16, nullptr, qpj, 8192, 1024, 1024, 1024, 0);
    gemm_bt<true ,false,false><<<dim3(8,64), 256, 0, stream>>>(fl, 1, qn, ipw32, ipb32, nullptr, qpj, 8192, 1024, 1024, 1024, 0);
    gemm_bt<false,false,false><<<dim3(8,64), 256, 0, stream>>>(fl, 0, kvn, ipw16 + 1048576, ipb16 + 1024, nullptr, kpj, 8192, 1024, 1024, 1024, 0);
    gemm_bt<true ,false,false><<<dim3(8,64), 256, 0, stream>>>(fl, 1, kvn, ipw32 + 1048576, ipb32 + 1024, nullptr, kpj, 8192, 1024, 1024, 1024, 0);
    gemm_bt<false,false,false><<<dim3(8,64), 256, 0, stream>>>(fl, 0, kvn, ipw16 + 2097152, ipb16 + 2048, nullptr, vpj, 8192, 1024, 1024, 1024, 0);
    gemm_bt<true ,false,false><<<dim3(8,64), 256, 0, stream>>>(fl, 1, kvn, ipw32 + 2097152, ipb32 + 2048, nullptr, vpj, 8192, 1024, 1024, 1024, 0);

    transpose_v<<<4096, 256, 0, stream>>>(vpj, vtr);
    flash_attn<<<dim3(8,64), 256, 0, stream>>>(qpj, kpj, vtr, cm, aco, ml);
    attn_mean_k<false><<<dim3(8,64), 256, 0, stream>>>(fl, 0, qpj, kpj, cm, ml, ow16);
    attn_mean_k<true ><<<dim3(8,64), 256, 0, stream>>>(fl, 1, qpj, kpj, cm, ml, ow32);

    // out-proj + residual(query) -> xbf (always fp32)
    gemm_bt<false,false,true><<<dim3(8,64), 256, 0, stream>>>(fl, 0, aco, opw, opb, query, xbf, 8192, 1024, 1024, 1024, 0);
    gemm_bt<true ,true ,true><<<dim3(8,64), 256, 0, stream>>>(fl, 1, aco, opw, opb, query, xbf, 8192, 1024, 1024, 1024, 0);

    // final LN: x input always fp32, weights follow global dtype
    ln_k<true,false><<<8192, 256, 0, stream>>>(fl, 0, xbf, lfw, lfb, hn);
    ln_k<true,true ><<<8192, 256, 0, stream>>>(fl, 1, xbf, lfw, lfb, hn);

    // FFN in two N=2048 chunks (g buffer is 32 MiB)
    // chunk a
    gemm_bt<false,false,false><<<dim3(16,64), 256, 0, stream>>>(fl, 0, hn, w116, b116, nullptr, g, 8192, 2048, 1024, 1024, 1);
    gemm_bt<true ,false,false><<<dim3(16,64), 256, 0, stream>>>(fl, 1, hn, w132, b132, nullptr, g, 8192, 2048, 1024, 1024, 1);
    gemm_bt<false,true ,true ><<<dim3(8,64), 256, 0, stream>>>(fl, 0, g, w216, (const unsigned short*)b2, xbf, xbf, 8192, 1024, 2048, 4096, 0);
    gemm_bt<true ,true ,true ><<<dim3(8,64), 256, 0, stream>>>(fl, 1, g, w232, (const float*)b2, xbf, xbf, 8192, 1024, 2048, 4096, 0);
    // chunk b
    gemm_bt<false,false,false><<<dim3(16,64), 256, 0, stream>>>(fl, 0, hn, w116 + (size_t)2048*1024, b116 + 2048, nullptr, g, 8192, 2048, 1024, 1024, 1);
    gemm_bt<true ,false,false><<<dim3(16,64), 256, 0, stream>>>(fl, 1, hn, w132 + (size_t)2048*1024, b132 + 2048, nullptr, g, 8192, 2048, 1024, 1024, 1);
    gemm_bt<false,true ,false><<<dim3(8,64), 256, 0, stream>>>(fl, 0, g, w216 + 2048, nullptr, xbf, d_out, 8192, 1024, 2048, 4096, 0);
    gemm_bt<true ,true ,true ><<<dim3(8,64), 256, 0, stream>>>(fl, 1, g, w232 + 2048, nullptr, xbf, d_out, 8192, 1024, 2048, 4096, 0);
}

// Round 4
// 1149.124 us; speedup vs baseline: 1.2708x; 1.2708x over previous
//
#include <hip/hip_runtime.h>
#include <math.h>

typedef short  s16x8 __attribute__((ext_vector_type(8)));
typedef short  s16x4 __attribute__((ext_vector_type(4)));
typedef float  f32x4 __attribute__((ext_vector_type(4)));

#define DEV static __device__ __forceinline__

DEV float b2f(unsigned short h) {
    unsigned int u = ((unsigned int)h) << 16;
    float f; __builtin_memcpy(&f, &u, 4); return f;
}
DEV unsigned short f2b(float f) {
    unsigned int u; __builtin_memcpy(&u, &f, 4);
    unsigned int r = (u + 0x7fffu + ((u >> 16) & 1u)) >> 16;
    return (unsigned short)r;
}

// 16B-per-lane async global->LDS. LDS dest is wave-uniform base; HW writes
// lane i at base + i*16.
#define GLD16(gp, lp) __builtin_amdgcn_global_load_lds( \
    (const __attribute__((address_space(1))) unsigned int*)(const void*)(gp), \
    (__attribute__((address_space(3))) unsigned int*)(void*)(lp), 16, 0, 0)

DEV float ldsel(const void* p, size_t i, bool f32) {
    return f32 ? ((const float*)p)[i] : b2f(((const unsigned short*)p)[i]);
}
DEV s16x8 ld8sel(const void* p, size_t eidx, bool f32) {
    if (f32) {
        const float* f = (const float*)p + eidx;
        f32x4 a = *(const f32x4*)f;
        f32x4 b = *(const f32x4*)(f + 4);
        s16x8 o;
        o[0]=(short)f2b(a[0]); o[1]=(short)f2b(a[1]); o[2]=(short)f2b(a[2]); o[3]=(short)f2b(a[3]);
        o[4]=(short)f2b(b[0]); o[5]=(short)f2b(b[1]); o[6]=(short)f2b(b[2]); o[7]=(short)f2b(b[3]);
        return o;
    }
    return *(const s16x8*)((const unsigned short*)p + eidx);
}

// ---------------------------------------------------------------------------
__global__ __launch_bounds__(256) void dtype_probe(
    const unsigned int* __restrict__ q, int* __restrict__ flag)
{
    int t = threadIdx.x;
    int hits = 0;
    for (int i = t; i < 2048; i += 256) {
        unsigned e0 = (q[i] >> 7) & 0xFFu;
        hits += (e0 >= 0x70u && e0 <= 0x87u) ? 1 : 0;
    }
#pragma unroll
    for (int m = 32; m >= 1; m >>= 1) hits += __shfl_xor(hits, m);
    __shared__ int sh[4];
    if ((t & 63) == 0) sh[t >> 6] = hits;
    __syncthreads();
    if (t == 0) *flag = (sh[0] + sh[1] + sh[2] + sh[3] > 1024) ? 0 : 1;
}

// ---------------------------------------------------------------------------
__global__ __launch_bounds__(1024) void mask_prep(
    const unsigned int* __restrict__ w, const unsigned char* __restrict__ bytes,
    int* __restrict__ clean)
{
    __shared__ int flag;
    const int t = threadIdx.x;
    if (t == 0) flag = 0;
    __syncthreads();
    unsigned int a = w[t], b = w[t + 1024];
    if (a > 1u || b > 1u) flag = 1;
    __syncthreads();
    const int f = flag;
#pragma unroll
    for (int i = 0; i < 8; i++) {
        int c = t * 8 + i;
        clean[c] = f ? (int)(bytes[c] != 0) : (int)(w[c] != 0);
    }
}

// ---------------------------------------------------------------------------
// Weight conversion -> contiguous bf16 (12592128 elements total).
// ---------------------------------------------------------------------------
struct CvtArgs { const void* s[8]; };
__global__ __launch_bounds__(256) void cvt_w(
    const int* __restrict__ flagp, CvtArgs a, unsigned short* __restrict__ dst)
{
    const int f = *flagp;
    size_t e = ((size_t)blockIdx.x * 256 + threadIdx.x) * 8;
    if (e >= 12592128u) return;
    const size_t off[9] = {0u, 3145728u, 4194304u, 8388608u, 12582912u,
                           12585984u, 12587008u, 12591104u, 12592128u};
    int s = 0;
    while (e >= off[s + 1]) s++;
    *(s16x8*)&dst[e] = ld8sel(a.s[s], e - off[s], f == 1);
}

// ---------------------------------------------------------------------------
// LayerNorm(1024). mode: 0=bf16, 1=fp32, 2=follow flag.
// ---------------------------------------------------------------------------
__global__ __launch_bounds__(256) void ln_k(
    const int* __restrict__ flagp, int xmode, int wmode,
    const void* __restrict__ x, const void* __restrict__ wgt,
    const void* __restrict__ bias, unsigned short* __restrict__ y)
{
    const int f = *flagp;
    const bool xf = (xmode == 2) ? (f == 1) : (xmode == 1);
    const bool wf = (wmode == 2) ? (f == 1) : (wmode == 1);
    const int row = blockIdx.x, t = threadIdx.x;
    const int w = t >> 6, lane = t & 63;
    float f0, f1, f2, f3;
    if (xf) {
        f32x4 v = *(const f32x4*)((const float*)x + (size_t)row * 1024 + t * 4);
        f0 = v[0]; f1 = v[1]; f2 = v[2]; f3 = v[3];
    } else {
        s16x4 v = *(const s16x4*)((const unsigned short*)x + (size_t)row * 1024 + t * 4);
        f0 = b2f((unsigned short)v[0]); f1 = b2f((unsigned short)v[1]);
        f2 = b2f((unsigned short)v[2]); f3 = b2f((unsigned short)v[3]);
    }
    __shared__ float red[4];
    float s = f0 + f1 + f2 + f3;
#pragma unroll
    for (int m = 32; m >= 1; m >>= 1) s += __shfl_xor(s, m);
    if (lane == 0) red[w] = s;
    __syncthreads();
    float mu = (red[0] + red[1] + red[2] + red[3]) * (1.0f / 1024.0f);
    float d0 = f0 - mu, d1 = f1 - mu, d2 = f2 - mu, d3 = f3 - mu;
    float q = d0 * d0 + d1 * d1 + d2 * d2 + d3 * d3;
#pragma unroll
    for (int m = 32; m >= 1; m >>= 1) q += __shfl_xor(q, m);
    __syncthreads();
    if (lane == 0) red[w] = q;
    __syncthreads();
    float var = (red[0] + red[1] + red[2] + red[3]) * (1.0f / 1024.0f);
    float rs = rsqrtf(var + 1e-5f);
    s16x4 vo;
    vo[0] = (short)f2b(d0 * rs * ldsel(wgt, t*4+0, wf) + ldsel(bias, t*4+0, wf));
    vo[1] = (short)f2b(d1 * rs * ldsel(wgt, t*4+1, wf) + ldsel(bias, t*4+1, wf));
    vo[2] = (short)f2b(d2 * rs * ldsel(wgt, t*4+2, wf) + ldsel(bias, t*4+2, wf));
    vo[3] = (short)f2b(d3 * rs * ldsel(wgt, t*4+3, wf) + ldsel(bias, t*4+3, wf));
    *(s16x4*)&y[(size_t)row * 1024 + t * 4] = vo;
}

// ---------------------------------------------------------------------------
// GEMM with global_load_lds staging (A always; W when bf16).
// wmode: 0 bf16, 2 follow-flag. bmode: -1 none, 0 bf16, 2 flag.
// rmode: 0 none, 1 bf16, 2 fp32, 3 flag(raw). omode: 0 bf16, 1 fp32, 2 flag.
// ---------------------------------------------------------------------------
__global__ __launch_bounds__(256) void gemm_bt(
    const int* __restrict__ flagp,
    const unsigned short* __restrict__ A,
    const void* __restrict__ W, size_t woff, int wmode,
    const void* __restrict__ bias, size_t boff, int bmode,
    const void* __restrict__ res, int rmode,
    void* __restrict__ C, int omode,
    int M, int N, int Kd, int ldw, int act)
{
    const int f = *flagp;
    const bool wf = (wmode == 2) && (f == 1);
    __shared__ alignas(16) unsigned short As[128 * 32];
    __shared__ alignas(16) unsigned short Bs[128 * 32];
    const int t = threadIdx.x;
    const int m0 = blockIdx.y * 128, n0 = blockIdx.x * 128;
    const int w = t >> 6, lane = t & 63, quad = lane >> 4, l16 = lane & 15;
    const int wm = (w >> 1) * 64, wn = (w & 1) * 64;
    const f32x4 zero = {0.f, 0.f, 0.f, 0.f};
    f32x4 acc[4][4];
#pragma unroll
    for (int i = 0; i < 4; i++)
#pragma unroll
        for (int j = 0; j < 4; j++) acc[i][j] = zero;
    const int r0 = t >> 2, c0 = (t & 3) * 8;
    unsigned short* AsW = As + (size_t)w * 512;   // wave-uniform LDS bases
    unsigned short* BsW = Bs + (size_t)w * 512;
    const unsigned short* W16 = (const unsigned short*)W + woff;
    const float*          W32 = (const float*)W + woff;

    for (int kt = 0; kt < Kd; kt += 32) {
        GLD16(&A[(size_t)(m0 + r0) * Kd + kt + c0],      AsW);
        GLD16(&A[(size_t)(m0 + r0 + 64) * Kd + kt + c0], AsW + 2048);
        if (wf) {
            *(s16x8*)&Bs[r0 * 32 + c0]        = ld8sel(W32, (size_t)(n0 + r0) * ldw + kt + c0, true);
            *(s16x8*)&Bs[(r0 + 64) * 32 + c0] = ld8sel(W32, (size_t)(n0 + r0 + 64) * ldw + kt + c0, true);
        } else {
            GLD16(&W16[(size_t)(n0 + r0) * ldw + kt + c0],      BsW);
            GLD16(&W16[(size_t)(n0 + r0 + 64) * ldw + kt + c0], BsW + 2048);
        }
        __syncthreads();
        s16x8 af[4], bfr[4];
#pragma unroll
        for (int i = 0; i < 4; i++) {
            af[i]  = *(const s16x8*)&As[(wm + i * 16 + l16) * 32 + quad * 8];
            bfr[i] = *(const s16x8*)&Bs[(wn + i * 16 + l16) * 32 + quad * 8];
        }
#pragma unroll
        for (int mi = 0; mi < 4; mi++)
#pragma unroll
            for (int ni = 0; ni < 4; ni++)
                acc[mi][ni] = __builtin_amdgcn_mfma_f32_16x16x32_bf16(af[mi], bfr[ni], acc[mi][ni], 0, 0, 0);
        __syncthreads();
    }
    const bool bf = (bmode == 2) && (f == 1);
    const bool rf = (rmode == 2) || (rmode == 3 && f == 1);
    const bool of = (omode == 1) || (omode == 2 && f == 1);
#pragma unroll
    for (int mi = 0; mi < 4; mi++)
#pragma unroll
        for (int ni = 0; ni < 4; ni++)
#pragma unroll
            for (int r = 0; r < 4; r++) {
                int gr = m0 + wm + mi * 16 + quad * 4 + r;
                int gc = n0 + wn + ni * 16 + l16;
                float v = acc[mi][ni][r];
                if (bmode >= 0) v += ldsel(bias, boff + gc, bf);
                if (act) v = 0.5f * v * (1.f + erff(v * 0.70710678118f));
                if (rmode) v += ldsel(res, (size_t)gr * N + gc, rf);
                size_t ci = (size_t)gr * N + gc;
                if (of) ((float*)C)[ci] = v;
                else ((unsigned short*)C)[ci] = f2b(v);
            }
}

// ---------------------------------------------------------------------------
__global__ __launch_bounds__(256) void transpose_v(
    const unsigned short* __restrict__ vp, unsigned short* __restrict__ vt)
{
    int t = blockIdx.x * 256 + threadIdx.x;
    int k8 = (t & 127) * 8;
    int d  = (t >> 7) & 63;
    int h  = (t >> 13) & 15;
    int b  = t >> 17;
    s16x8 v;
#pragma unroll
    for (int j = 0; j < 8; j++)
        v[j] = (short)vp[(size_t)((b << 10) + k8 + j) * 1024 + (h << 6) + d];
    *(s16x8*)&vt[(size_t)t * 8] = v;
}

// ---------------------------------------------------------------------------
// Flash attention: wave = (b, h, 16 q-rows); grid (128, 16) x 256 thr.
// NO barriers; per-wave parity-double-buffered P + lgkmcnt waits.
// ---------------------------------------------------------------------------
__global__ __launch_bounds__(256) void flash_attn(
    const unsigned short* __restrict__ qp, const unsigned short* __restrict__ kp,
    const unsigned short* __restrict__ vt, const int* __restrict__ mask,
    unsigned short* __restrict__ ao, float* __restrict__ ml)
{
    const int bh = blockIdx.x;
    const int b = bh >> 4, h = bh & 15;
    const int t = threadIdx.x, w = t >> 6, lane = t & 63, quad = lane >> 4, l16 = lane & 15;
    const int q0 = (blockIdx.y * 4 + w) * 16;
    __shared__ unsigned short Pst[4][2][16 * 40];
    const float NEGINF = -__builtin_inff();
    const f32x4 zero = {0.f, 0.f, 0.f, 0.f};

    s16x8 qf0 = *(const s16x8*)&qp[(size_t)(b * 1024 + q0 + l16) * 1024 + h * 64 + quad * 8];
    s16x8 qf1 = *(const s16x8*)&qp[(size_t)(b * 1024 + q0 + l16) * 1024 + h * 64 + 32 + quad * 8];

    f32x4 O[4];
    float m_r[4], l_r[4];
#pragma unroll
    for (int dt = 0; dt < 4; dt++) O[dt] = zero;
#pragma unroll
    for (int r = 0; r < 4; r++) { m_r[r] = NEGINF; l_r[r] = 0.f; }

    for (int kt = 0; kt < 1024; kt += 32) {
        unsigned short* P = Pst[w][(kt >> 5) & 1];
        const int c0i = kt + l16, c1i = c0i + 16;
        const bool v0 = mask[b * 1024 + c0i] != 0;
        const bool v1 = mask[b * 1024 + c1i] != 0;
        const size_t kb0 = (size_t)(b * 1024 + c0i) * 1024 + h * 64 + quad * 8;
        const size_t kb1 = (size_t)(b * 1024 + c1i) * 1024 + h * 64 + quad * 8;
        s16x8 b00 = *(const s16x8*)&kp[kb0];
        s16x8 b01 = *(const s16x8*)&kp[kb0 + 32];
        s16x8 b10 = *(const s16x8*)&kp[kb1];
        s16x8 b11 = *(const s16x8*)&kp[kb1 + 32];
        f32x4 S0 = __builtin_amdgcn_mfma_f32_16x16x32_bf16(qf0, b00, zero, 0, 0, 0);
        S0 = __builtin_amdgcn_mfma_f32_16x16x32_bf16(qf1, b01, S0, 0, 0, 0);
        f32x4 S1 = __builtin_amdgcn_mfma_f32_16x16x32_bf16(qf0, b10, zero, 0, 0, 0);
        S1 = __builtin_amdgcn_mfma_f32_16x16x32_bf16(qf1, b11, S1, 0, 0, 0);
        float e0[4], e1[4];
#pragma unroll
        for (int r = 0; r < 4; r++) {
            float s0 = v0 ? S0[r] * 0.125f : NEGINF;
            float s1 = v1 ? S1[r] * 0.125f : NEGINF;
            float mt = fmaxf(s0, s1);
#pragma unroll
            for (int off = 1; off < 16; off <<= 1) mt = fmaxf(mt, __shfl_xor(mt, off));
            float mo = m_r[r];
            float mn = fmaxf(mo, mt);
            float al = (mo == NEGINF) ? 0.f : __expf(mo - mn);
            float x0 = v0 ? __expf(s0 - mn) : 0.f;
            float x1 = v1 ? __expf(s1 - mn) : 0.f;
            float rsum = x0 + x1;
#pragma unroll
            for (int off = 1; off < 16; off <<= 1) rsum += __shfl_xor(rsum, off);
            m_r[r] = mn;
            l_r[r] = l_r[r] * al + rsum;
#pragma unroll
            for (int dt = 0; dt < 4; dt++) O[dt][r] *= al;
            e0[r] = x0; e1[r] = x1;
        }
        asm volatile("" ::: "memory");
#pragma unroll
        for (int r = 0; r < 4; r++) {
            P[(quad * 4 + r) * 40 + l16]      = f2b(e0[r]);
            P[(quad * 4 + r) * 40 + 16 + l16] = f2b(e1[r]);
        }
        asm volatile("s_waitcnt lgkmcnt(0)" ::: "memory");
        s16x8 pf = *(const s16x8*)&P[l16 * 40 + quad * 8];
        asm volatile("" ::: "memory");
#pragma unroll
        for (int dt = 0; dt < 4; dt++) {
            s16x8 vf = *(const s16x8*)&vt[(size_t)((b * 16 + h) * 64 + dt * 16 + l16) * 1024 + kt + quad * 8];
            O[dt] = __builtin_amdgcn_mfma_f32_16x16x32_bf16(pf, vf, O[dt], 0, 0, 0);
        }
    }
    float li[4];
#pragma unroll
    for (int r = 0; r < 4; r++)
        li[r] = (l_r[r] > 0.f) ? 1.f / l_r[r] : 0.f;
#pragma unroll
    for (int dt = 0; dt < 4; dt++)
#pragma unroll
        for (int r = 0; r < 4; r++) {
            int qrow = q0 + quad * 4 + r;
            ao[(size_t)(b * 1024 + qrow) * 1024 + h * 64 + dt * 16 + l16] = f2b(O[dt][r] * li[r]);
        }
    if (l16 == 0) {
#pragma unroll
        for (int r = 0; r < 4; r++) {
            int qrow = q0 + quad * 4 + r;
            size_t ix = ((size_t)(b * 16 + h) * 1024 + qrow) * 2;
            ml[ix] = m_r[r]; ml[ix + 1] = l_r[r];
        }
    }
}

// ---------------------------------------------------------------------------
// Mean-over-heads attention weights. Writes to d_out at element offset 8M
// (dtype-dependent byte offset handled in-kernel via the flag).
// ---------------------------------------------------------------------------
__global__ __launch_bounds__(256) void attn_mean_k(
    const int* __restrict__ flagp,
    const unsigned short* __restrict__ qp, const unsigned short* __restrict__ kp,
    const int* __restrict__ mask, const float* __restrict__ ml,
    void* __restrict__ dout)
{
    const bool of = (*flagp == 1);
    const size_t SHIFT = (size_t)8 * 1024 * 1024;
    const int b = blockIdx.x, q0 = blockIdx.y * 16;
    const int t = threadIdx.x, w = t >> 6, lane = t & 63, quad = lane >> 4, l16 = lane & 15;
    const int kbase = w * 256;
    const f32x4 zero = {0.f, 0.f, 0.f, 0.f};
    f32x4 acc[16];
#pragma unroll
    for (int i = 0; i < 16; i++) acc[i] = zero;
    unsigned vm = 0;
#pragma unroll
    for (int i = 0; i < 16; i++)
        if (mask[b * 1024 + kbase + i * 16 + l16]) vm |= 1u << i;
    for (int h = 0; h < 16; h++) {
        const size_t qb = (size_t)(b * 1024 + q0 + l16) * 1024 + h * 64 + quad * 8;
        s16x8 a0 = *(const s16x8*)&qp[qb];
        s16x8 a1 = *(const s16x8*)&qp[qb + 32];
        float mrow[4], lirow[4];
#pragma unroll
        for (int r = 0; r < 4; r++) {
            size_t ix = ((size_t)(b * 16 + h) * 1024 + q0 + quad * 4 + r) * 2;
            float lv = ml[ix + 1];
            mrow[r] = ml[ix]; lirow[r] = (lv > 0.f) ? 1.f / lv : 0.f;
        }
#pragma unroll
        for (int i = 0; i < 16; i++) {
            const size_t kb = (size_t)(b * 1024 + kbase + i * 16 + l16) * 1024 + h * 64 + quad * 8;
            s16x8 b0 = *(const s16x8*)&kp[kb];
            s16x8 b1 = *(const s16x8*)&kp[kb + 32];
            f32x4 S = __builtin_amdgcn_mfma_f32_16x16x32_bf16(a0, b0, zero, 0, 0, 0);
            S = __builtin_amdgcn_mfma_f32_16x16x32_bf16(a1, b1, S, 0, 0, 0);
            if ((vm >> i) & 1) {
#pragma unroll
                for (int r = 0; r < 4; r++)
                    acc[i][r] += __expf(S[r] * 0.125f - mrow[r]) * lirow[r];
            }
        }
    }
#pragma unroll
    for (int i = 0; i < 16; i++)
#pragma unroll
        for (int r = 0; r < 4; r++) {
            int qrow = q0 + quad * 4 + r;
            size_t oi = SHIFT + (size_t)(b * 1024 + qrow) * 1024 + kbase + i * 16 + l16;
            float v = acc[i][r] * 0.0625f;
            if (of) ((float*)dout)[oi] = v;
            else ((unsigned short*)dout)[oi] = f2b(v);
        }
}

// ---------------------------------------------------------------------------
extern "C" void kernel_launch(void* const* d_in, const int* in_sizes, int n_in,
                              void* d_out, int out_size, void* d_ws, size_t ws_size,
                              hipStream_t stream) {
    const void* query = d_in[0];
    const void* keyv  = d_in[1];
    const void* maskr = d_in[2];
    const void* lqw = d_in[3];  const void* lqb = d_in[4];
    const void* lkw = d_in[5];  const void* lkb = d_in[6];
    const void* lfw = d_in[7];  const void* lfb = d_in[8];
    const void* ipw = d_in[9];  const void* ipb = d_in[10];
    const void* opw = d_in[11]; const void* opb = d_in[12];
    const void* w1  = d_in[13]; const void* b1  = d_in[14];
    const void* w2  = d_in[15]; const void* b2  = d_in[16];

    char* ws = (char*)d_ws;
    const size_t MB = 1024 * 1024;
    unsigned short* qn  = (unsigned short*)(ws + 0 * MB);
    unsigned short* kvn = (unsigned short*)(ws + 16 * MB);
    unsigned short* qpj = (unsigned short*)(ws + 32 * MB);
    unsigned short* kpj = (unsigned short*)(ws + 48 * MB);
    unsigned short* vpj = (unsigned short*)(ws + 64 * MB);
    unsigned short* vtr = (unsigned short*)(ws + 80 * MB);
    float*          ml  = (float*)(ws + 96 * MB);
    int*            cm  = (int*)(ws + 97 * MB);
    int*            fl  = (int*)(ws + 97 * MB + 256 * 1024);
    unsigned short* aco = (unsigned short*)(ws + 0 * MB);
    float*          xbf = (float*)(ws + 16 * MB);
    unsigned short* hn  = (unsigned short*)(ws + 48 * MB);
    unsigned short* g   = (unsigned short*)(ws + 64 * MB);
    unsigned short* wc  = (unsigned short*)(ws + 98 * MB);

    const bool big = ws_size >= (size_t)125 * MB;
    const size_t cWq = 0, cWk = 1048576, cWv = 2097152, cWo = 3145728;
    const size_t cW1 = 4194304, cW2 = 8388608;
    const size_t cBq = 12582912, cBo = 12585984, cB1 = 12587008, cB2 = 12591104;

    const void *Wq, *Wk, *Wv, *Wo, *Wf1, *Wf2, *Bq, *Bo, *Bf1, *Bf2;
    size_t wq_o, wk_o, wv_o, wo_o, w1_o, w2_o, bq_o, bk_o, bv_o, bo_o, b1_o, b2_o;
    int wm, bm;
    if (big) {
        Wq = Wk = Wv = Wo = Wf1 = Wf2 = Bq = Bo = Bf1 = Bf2 = wc;
        wq_o = cWq; wk_o = cWk; wv_o = cWv; wo_o = cWo; w1_o = cW1; w2_o = cW2;
        bq_o = cBq; bk_o = cBq + 1024; bv_o = cBq + 2048; bo_o = cBo; b1_o = cB1; b2_o = cB2;
        wm = 0; bm = 0;
    } else {
        Wq = Wk = Wv = ipw; Wo = opw; Wf1 = w1; Wf2 = w2;
        Bq = ipb; Bo = opb; Bf1 = b1; Bf2 = b2;
        wq_o = 0; wk_o = 1048576; wv_o = 2097152; wo_o = 0; w1_o = 0; w2_o = 0;
        bq_o = 0; bk_o = 1024; bv_o = 2048; bo_o = 0; b1_o = 0; b2_o = 0;
        wm = 2; bm = 2;
    }

    dtype_probe<<<1, 256, 0, stream>>>((const unsigned int*)query, fl);
    mask_prep<<<1, 1024, 0, stream>>>((const unsigned int*)maskr, (const unsigned char*)maskr, cm);
    if (big) {
        CvtArgs ca; ca.s[0] = ipw; ca.s[1] = opw; ca.s[2] = w1; ca.s[3] = w2;
        ca.s[4] = ipb; ca.s[5] = opb; ca.s[6] = b1; ca.s[7] = b2;
        cvt_w<<<6149, 256, 0, stream>>>(fl, ca, wc);
    }

    ln_k<<<8192, 256, 0, stream>>>(fl, 2, 2, query, lqw, lqb, qn);
    ln_k<<<8192, 256, 0, stream>>>(fl, 2, 2, keyv, lkw, lkb, kvn);

    gemm_bt<<<dim3(8, 64), 256, 0, stream>>>(fl, qn,  Wq, wq_o, wm, Bq, bq_o, bm,
                                             nullptr, 0, qpj, 0, 8192, 1024, 1024, 1024, 0);
    gemm_bt<<<dim3(8, 64), 256, 0, stream>>>(fl, kvn, Wk, wk_o, wm, Bq, bk_o, bm,
                                             nullptr, 0, kpj, 0, 8192, 1024, 1024, 1024, 0);
    gemm_bt<<<dim3(8, 64), 256, 0, stream>>>(fl, kvn, Wv, wv_o, wm, Bq, bv_o, bm,
                                             nullptr, 0, vpj, 0, 8192, 1024, 1024, 1024, 0);

    transpose_v<<<4096, 256, 0, stream>>>(vpj, vtr);
    flash_attn<<<dim3(128, 16), 256, 0, stream>>>(qpj, kpj, vtr, cm, aco, ml);
    attn_mean_k<<<dim3(8, 64), 256, 0, stream>>>(fl, qpj, kpj, cm, ml, d_out);

    gemm_bt<<<dim3(8, 64), 256, 0, stream>>>(fl, aco, Wo, wo_o, wm, Bo, bo_o, bm,
                                             query, 3, xbf, 1, 8192, 1024, 1024, 1024, 0);
    ln_k<<<8192, 256, 0, stream>>>(fl, 1, 2, xbf, lfw, lfb, hn);

    gemm_bt<<<dim3(16, 64), 256, 0, stream>>>(fl, hn, Wf1, w1_o, wm, Bf1, b1_o, bm,
                                              nullptr, 0, g, 0, 8192, 2048, 1024, 1024, 1);
    gemm_bt<<<dim3(8, 64), 256, 0, stream>>>(fl, g, Wf2, w2_o, wm, Bf2, b2_o, bm,
                                             xbf, 2, xbf, 1, 8192, 1024, 2048, 4096, 0);
    gemm_bt<<<dim3(16, 64), 256, 0, stream>>>(fl, hn, Wf1, w1_o + (size_t)2048 * 1024, wm,
                                              Bf1, b1_o + 2048, bm,
                                              nullptr, 0, g, 0, 8192, 2048, 1024, 1024, 1);
    gemm_bt<<<dim3(8, 64), 256, 0, stream>>>(fl, g, Wf2, w2_o + 2048, wm,
                                             nullptr, 0, -1,
                                             xbf, 2, d_out, 2, 8192, 1024, 2048, 4096, 0);
}